// Round 8
// baseline (1129.547 us; speedup 1.0000x reference)
//
#include <hip/hip_runtime.h>
#include <math.h>

#define H      1024
#define NA     512
#define NI     256
#define SEQ    4096
#define BATCH  4
#define NTOK   (BATCH*SEQ)      // 16384
#define SINKN  4
#define RECENTN 19
#define MIDN   (SEQ - SINKN - RECENTN)   // 4073
#define KSEL   2025
#define CHK    16

#define TT   128                // tokens per tile
#define UT   128                // units per tile
#define KC   16                 // k-chunk staged in LDS
#define NCH  (H/KC)             // 64 chunks (FULL K per block - v7's k-split
                                // was invalid: relu(x1+x2) != relu(x1)+relu(x2))
#define ATT_BLOCKS 512          // 128 token-tiles * 4 unit-passes
#define IMP_BLOCKS 256          // 128 token-tiles * 2 unit-passes

// async global->LDS, 16B per lane, dest = wave-uniform base + lane*16
__device__ __forceinline__ void dma16(const float* g, float* l)
{
    __builtin_amdgcn_global_load_lds(
        (const __attribute__((address_space(1))) void*)g,
        (__attribute__((address_space(3))) void*)l, 16, 0, 0);
}

// ---------------------------------------------------------------------------
// Kernel 1 (v8): 128tok x 128unit x FULL-K tile, 128 threads, 8x16 per-thread
// register tile. Keeps v7's LDS-read ratio win (6 b128 per 128 FMA -> LDS pipe
// 442K cyc/CU vs VALU 393K) while restoring correctness: relu+W2 applied only
// after the complete 1024-term layer-1 sum. Grid = 768 blocks = 3/CU
// (6 waves/CU; 128 independent FMAs/thread/h give the ILP to self-hide reads).
// Bank layout (lane-enumerated):
//  - B [KC][128] staged by dma16 (linear dest); global source pre-swizzled by
//    the involution sig(q)=q^(q>>3) on 16B quads; reads at sig(4*U16+r) hit
//    all 8 bank-groups (conflict-free).
//  - A [KC][128] transposed; logical token-quad c stored at c ^ (rho<<1),
//    rho=(h>>2)&3. Writes 2-way (free); reads 8 addrs over 4 groups (2-way).
//  - A prefetch in 4 NAMED float4 scalars (arrays go to scratch - v3/v5).
// Slot layout = unit-pass x full K, identical semantics to passing v6 ->
// select_kernel unchanged. Deterministic summation order throughout.
// ---------------------------------------------------------------------------
__global__ __launch_bounds__(128, 2) void score_gemm_kernel(
    const float* __restrict__ keys, const float* __restrict__ values,
    const float* __restrict__ W1a, const float* __restrict__ b1a,
    const float* __restrict__ W2a,
    const float* __restrict__ W1i, const float* __restrict__ b1i,
    const float* __restrict__ W2i,
    float* __restrict__ part)
{
    __shared__ __align__(16) float smem[KC * 128 + 2 * KC * 128];   // 24 KB
    float* A_lds = smem;                 // [KC][128] transposed, quad-swizzled
    float* Bbuf  = smem + KC * 128;      // 2 x [KC][128], linear (DMA dest)

    const int tid = threadIdx.x;         // 0..127
    const int lw  = tid & 63;
    const int w   = tid >> 6;            // wave 0..1
    const int bid = blockIdx.x;

    const bool is_att = bid < ATT_BLOCKS;
    const int  lb     = is_att ? bid : bid - ATT_BLOCKS;
    const int  tile   = is_att ? (lb >> 2) : (lb >> 1);
    const int  upass  = is_att ? (lb & 3)  : (lb & 1);
    const int  slot   = is_att ? upass : 4 + upass;
    const int  tokb   = tile * TT;
    const int  u0     = upass * UT;
    const int  wstride = is_att ? NA : NI;

    const float* Aptr  = is_att ? keys : values;
    const float* Wbase = (is_att ? W1a : W1i) + u0;
    const float* b1p   = (is_att ? b1a : b1i) + u0;
    const float* w2p   = (is_att ? W2a : W2i) + u0;

    // thread tile: tokens 8*T8..+7, units u0 + 16*U16..+15
    const int T8  = tid >> 3;            // 0..15
    const int U16 = tid & 7;             // 0..7

    // B read offsets: logical quad q=4*U16+r at phys sig(q)=q^(q>>3)
    const int q0 = 4 * U16, q1 = q0 + 1, q2 = q0 + 2, q3 = q0 + 3;
    const int bof0 = (q0 ^ (q0 >> 3)) << 2;
    const int bof1 = (q1 ^ (q1 >> 3)) << 2;
    const int bof2 = (q2 ^ (q2 >> 3)) << 2;
    const int bof3 = (q3 ^ (q3 >> 3)) << 2;

    // A staging: thread loads tokens {at0,+32,+64,+96}, h-quad aq of chunk.
    const int at0 = tid >> 2;            // 0..31
    const int aq  = tid & 3;             // h-quad in chunk; rho(row)=aq
    const float* aS = Aptr + (size_t)(tokb + at0) * H + aq * 4;
    // phys col = 4*((tok>>2)^(aq<<1)) + (tok&3); +32p tokens -> +32p floats
    const int awb = (aq * 4) * 128 + ((((at0 >> 2) ^ (aq << 1))) << 2) + (at0 & 3);

    // B DMA: wave w call k covers rows {4k+2w, 4k+2w+1}; lane lw writes phys
    // quad (lw&31) of row +(lw>>5); content = logical quad sig(lw&31).
    const int sq   = lw & 31;
    const int sigq = sq ^ (sq >> 3);
    const float* bS = Wbase + (size_t)(2 * w + (lw >> 5)) * wstride + sigq * 4;
    const int brow = 2 * w;              // + 4k per call

    float acc[8][16];
#pragma unroll
    for (int t = 0; t < 8; ++t)
#pragma unroll
        for (int u = 0; u < 16; ++u) acc[t][u] = 0.f;

    // ---- prologue: chunk 0 in flight ----
    float4 aL0 = *(const float4*)(aS);
    float4 aL1 = *(const float4*)(aS + (size_t)32 * H);
    float4 aL2 = *(const float4*)(aS + (size_t)64 * H);
    float4 aL3 = *(const float4*)(aS + (size_t)96 * H);
    dma16(bS + (size_t) 0 * wstride, Bbuf + (brow +  0) * 128);
    dma16(bS + (size_t) 4 * wstride, Bbuf + (brow +  4) * 128);
    dma16(bS + (size_t) 8 * wstride, Bbuf + (brow +  8) * 128);
    dma16(bS + (size_t)12 * wstride, Bbuf + (brow + 12) * 128);

    for (int c = 0; c < NCH; ++c) {
        float* Bcur = Bbuf + (c & 1) * (KC * 128);
        float* Bnxt = Bbuf + ((c + 1) & 1) * (KC * 128);

        __syncthreads();     // drains loads/DMA issued one compute-phase ago
        A_lds[awb +  0 + 0 * 128] = aL0.x;
        A_lds[awb +  0 + 1 * 128] = aL0.y;
        A_lds[awb +  0 + 2 * 128] = aL0.z;
        A_lds[awb +  0 + 3 * 128] = aL0.w;
        A_lds[awb + 32 + 0 * 128] = aL1.x;
        A_lds[awb + 32 + 1 * 128] = aL1.y;
        A_lds[awb + 32 + 2 * 128] = aL1.z;
        A_lds[awb + 32 + 3 * 128] = aL1.w;
        A_lds[awb + 64 + 0 * 128] = aL2.x;
        A_lds[awb + 64 + 1 * 128] = aL2.y;
        A_lds[awb + 64 + 2 * 128] = aL2.z;
        A_lds[awb + 64 + 3 * 128] = aL2.w;
        A_lds[awb + 96 + 0 * 128] = aL3.x;
        A_lds[awb + 96 + 1 * 128] = aL3.y;
        A_lds[awb + 96 + 2 * 128] = aL3.z;
        A_lds[awb + 96 + 3 * 128] = aL3.w;
        __syncthreads();     // nothing in vmem flight -> cheap drain

        if (c + 1 < NCH) {   // issue next chunk; lands by next top-barrier
            const int hn = (c + 1) * KC;
            aL0 = *(const float4*)(aS + hn);
            aL1 = *(const float4*)(aS + hn + (size_t)32 * H);
            aL2 = *(const float4*)(aS + hn + (size_t)64 * H);
            aL3 = *(const float4*)(aS + hn + (size_t)96 * H);
            const float* bgn = bS + (size_t)hn * wstride;
            dma16(bgn + (size_t) 0 * wstride, Bnxt + (brow +  0) * 128);
            dma16(bgn + (size_t) 4 * wstride, Bnxt + (brow +  4) * 128);
            dma16(bgn + (size_t) 8 * wstride, Bnxt + (brow +  8) * 128);
            dma16(bgn + (size_t)12 * wstride, Bnxt + (brow + 12) * 128);
        }

#pragma unroll
        for (int h = 0; h < KC; ++h) {
            const int rho = (h >> 2) & 3;
            const int ofa = h * 128 + (((2 * T8) ^ (rho << 1)) << 2);
            float a[8], b[8];
            *(float4*)&a[0] = *(const float4*)&A_lds[ofa];       // tokens 8T8..+3
            *(float4*)&a[4] = *(const float4*)&A_lds[ofa + 4];   // tokens 8T8+4..+7
            *(float4*)&b[0] = *(const float4*)&Bcur[h * 128 + bof0];
            *(float4*)&b[4] = *(const float4*)&Bcur[h * 128 + bof1];
#pragma unroll
            for (int t = 0; t < 8; ++t)
#pragma unroll
                for (int u = 0; u < 8; ++u)
                    acc[t][u] = fmaf(a[t], b[u], acc[t][u]);
            *(float4*)&b[0] = *(const float4*)&Bcur[h * 128 + bof2];
            *(float4*)&b[4] = *(const float4*)&Bcur[h * 128 + bof3];
#pragma unroll
            for (int t = 0; t < 8; ++t)
#pragma unroll
                for (int u = 0; u < 8; ++u)
                    acc[t][8 + u] = fmaf(a[t], b[u], acc[t][8 + u]);
        }
    }

    // ---- epilogue: relu + second-layer slice -> per-token partial ----
    float s[8];
#pragma unroll
    for (int t = 0; t < 8; ++t) s[t] = 0.f;
#pragma unroll
    for (int qu = 0; qu < 4; ++qu) {     // units ascending
        const float4 b1q = *(const float4*)(b1p + U16 * 16 + qu * 4);
        const float4 w2q = *(const float4*)(w2p + U16 * 16 + qu * 4);
#pragma unroll
        for (int t = 0; t < 8; ++t) {
            s[t] += fmaxf(acc[t][qu * 4 + 0] + b1q.x, 0.f) * w2q.x;
            s[t] += fmaxf(acc[t][qu * 4 + 1] + b1q.y, 0.f) * w2q.y;
            s[t] += fmaxf(acc[t][qu * 4 + 2] + b1q.z, 0.f) * w2q.z;
            s[t] += fmaxf(acc[t][qu * 4 + 3] + b1q.w, 0.f) * w2q.w;
        }
    }

    __syncthreads();                     // done with staging LDS
    float* red = smem;                   // [TT][9] padded
#pragma unroll
    for (int t = 0; t < 8; ++t)
        red[(T8 * 8 + t) * 9 + U16] = s[t];
    __syncthreads();
    if (tid < TT) {
        float sv = 0.f;
        for (int x = 0; x < 8; ++x) sv += red[tid * 9 + x];   // fixed order
        part[(size_t)slot * NTOK + tokb + tid] = sv;
    }
}

// ---------------------------------------------------------------------------
// block-wide sum (256 threads), result broadcast to all threads
// ---------------------------------------------------------------------------
__device__ __forceinline__ int block_sum(int val, int* red, int tid)
{
#pragma unroll
    for (int off = 32; off > 0; off >>= 1) val += __shfl_down(val, off);
    if ((tid & 63) == 0) red[tid >> 6] = val;
    __syncthreads();
    const int total = red[0] + red[1] + red[2] + red[3];
    __syncthreads();
    return total;
}

// ---------------------------------------------------------------------------
// Kernel 2: combine partials into scores (fixed order) + per-row exact
// top-KSEL via 4-pass byte-radix select with parallel scans -> float mask.
// ---------------------------------------------------------------------------
__global__ __launch_bounds__(256) void select_kernel(
    const float* __restrict__ part, const float* __restrict__ b2a,
    const float* __restrict__ b2i, float* __restrict__ mask)
{
    __shared__ unsigned int ks[MIDN];
    __shared__ int hist[256];
    __shared__ int red[4];
    __shared__ int scan_s[256];
    __shared__ unsigned int sh_pref;
    __shared__ int sh_r;

    const int tid = threadIdx.x;
    const int row = blockIdx.x;
    const float ba  = b2a[0];
    const float bi2 = b2i[0];

    for (int i = tid; i < MIDN; i += 256) {
        const int tok = row * SEQ + SINKN + i;
        float sa = ((part[tok] + part[NTOK + tok]) + part[2 * NTOK + tok]) + part[3 * NTOK + tok];
        float si = part[4 * NTOK + tok] + part[5 * NTOK + tok];
        const float att = 1.f / (1.f + expf(-(sa + ba)));
        const float s = 0.6f * att + 0.4f * (si + bi2);
        unsigned int u = __float_as_uint(s);
        u = (u & 0x80000000u) ? ~u : (u | 0x80000000u);   // order-preserving map
        ks[i] = u;
    }
    if (tid == 0) { sh_pref = 0u; sh_r = KSEL; }
    __syncthreads();

    // byte-radix: after 4 passes sh_pref == KSEL-th largest key value
    for (int b = 3; b >= 0; --b) {
        hist[tid] = 0;
        __syncthreads();
        const unsigned int hi_mask = (b == 3) ? 0u : (0xFFFFFFFFu << ((b + 1) * 8));
        const unsigned int pref = sh_pref;
        for (int i = tid; i < MIDN; i += 256) {
            const unsigned int u = ks[i];
            if ((u & hi_mask) == pref)
                atomicAdd(&hist[(u >> (b * 8)) & 255], 1);
        }
        __syncthreads();

        // inclusive suffix-sum of hist (Hillis-Steele, 8 rounds)
        scan_s[tid] = hist[tid];
        __syncthreads();
#pragma unroll
        for (int off = 1; off < 256; off <<= 1) {
            const int add = (tid + off < 256) ? scan_s[tid + off] : 0;
            __syncthreads();
            scan_s[tid] += add;
            __syncthreads();
        }
        const int r    = sh_r;
        const int sfx  = scan_s[tid];
        const int sfx1 = (tid < 255) ? scan_s[tid + 1] : 0;
        if (sfx >= r && sfx1 < r) {      // unique winner
            sh_r = r - sfx1;
            sh_pref = pref | ((unsigned int)tid << (b * 8));
        }
        __syncthreads();
    }
    const unsigned int v = sh_pref;

    const int st = tid * CHK;
    const int en = (st + CHK < MIDN) ? (st + CHK) : MIDN;

    int cgt = 0, ceq = 0;
    for (int k = st; k < en; ++k) { cgt += (ks[k] > v) ? 1 : 0; ceq += (ks[k] == v) ? 1 : 0; }
    const int total_gt = block_sum(cgt, red, tid);
    const int need = KSEL - total_gt;    // #ties to keep (>=1 by construction)

    // exclusive prefix-sum of tie counts (parallel)
    scan_s[tid] = ceq;
    __syncthreads();
#pragma unroll
    for (int off = 1; off < 256; off <<= 1) {
        const int add = (tid >= off) ? scan_s[tid - off] : 0;
        __syncthreads();
        scan_s[tid] += add;
        __syncthreads();
    }
    int r = scan_s[tid] - ceq;           // exclusive prefix

    float* mr = mask + row * SEQ;
    for (int k = st; k < en; ++k) {
        const unsigned int u = ks[k];
        bool keep = false;
        if (u > v) keep = true;
        else if (u == v) { keep = (r < need); ++r; }
        mr[SINKN + k] = keep ? 1.f : 0.f;
    }
    for (int s = tid; s < SEQ; s += 256) {
        if (s < SINKN || s >= SEQ - RECENTN) mr[s] = 1.f;
    }
}

// ---------------------------------------------------------------------------
// Kernel 3: out = concat(keys*mask, values*mask), float4 grid-stride.
// ---------------------------------------------------------------------------
__global__ __launch_bounds__(256) void apply_kernel(
    const float* __restrict__ keys, const float* __restrict__ values,
    const float* __restrict__ mask, float* __restrict__ out)
{
    const int QT = NTOK * H / 4;          // 4194304 float4 per tensor
    const int stride = gridDim.x * 256;
    for (int i4 = blockIdx.x * 256 + threadIdx.x; i4 < 2 * QT; i4 += stride) {
        const bool isv = (i4 >= QT);
        const int  j4  = isv ? (i4 - QT) : i4;
        const float m  = mask[j4 >> 8];   // 256 float4 per token row
        const float4* src = isv ? (const float4*)values : (const float4*)keys;
        const float4 x = src[j4];
        float4 y; y.x = x.x * m; y.y = x.y * m; y.z = x.z * m; y.w = x.w * m;
        ((float4*)out)[i4] = y;
    }
}

extern "C" void kernel_launch(void* const* d_in, const int* in_sizes, int n_in,
                              void* d_out, int out_size, void* d_ws, size_t ws_size,
                              hipStream_t stream)
{
    const float* keys   = (const float*)d_in[0];
    const float* values = (const float*)d_in[1];
    const float* W1a = (const float*)d_in[2];
    const float* b1a = (const float*)d_in[3];
    const float* W2a = (const float*)d_in[4];
    const float* b2a = (const float*)d_in[5];
    const float* W1i = (const float*)d_in[6];
    const float* b1i = (const float*)d_in[7];
    const float* W2i = (const float*)d_in[8];
    const float* b2i = (const float*)d_in[9];

    float* part = (float*)d_ws;            // 6*NTOK floats (att 0-3, imp 4-5)
    float* mask = part + 6 * NTOK;         // NTOK floats

    score_gemm_kernel<<<ATT_BLOCKS + IMP_BLOCKS, 128, 0, stream>>>(
        keys, values, W1a, b1a, W2a, W1i, b1i, W2i, part);
    select_kernel<<<BATCH, 256, 0, stream>>>(part, b2a, b2i, mask);
    apply_kernel<<<8192, 256, 0, stream>>>(keys, values, mask, (float*)d_out);
}

// Round 9
// 544.932 us; speedup vs baseline: 2.0728x; 2.0728x over previous
//
#include <hip/hip_runtime.h>
#include <math.h>

#define H      1024
#define NA     512
#define NI     256
#define SEQ    4096
#define BATCH  4
#define NTOK   (BATCH*SEQ)      // 16384
#define SINKN  4
#define RECENTN 19
#define MIDN   (SEQ - SINKN - RECENTN)   // 4073
#define KSEL   2025
#define CHK    16

#define TT   128                // tokens per tile
#define UT   128                // units per tile
#define KC   32                 // k-chunk staged in LDS
#define NCH  (H/KC)             // 32 chunks
#define ATT_BLOCKS ((NTOK/TT) * (NA/UT))   // 512
#define IMP_BLOCKS ((NTOK/TT) * (NI/UT))   // 256

// async global->LDS, 16B per lane, dest = wave-uniform base + lane*16
__device__ __forceinline__ void dma16(const float* g, float* l)
{
    __builtin_amdgcn_global_load_lds(
        (const __attribute__((address_space(1))) void*)g,
        (__attribute__((address_space(3))) void*)l, 16, 0, 0);
}

// ---------------------------------------------------------------------------
// Kernel 1 (v9 = v6 + 3 blocks/CU): 128x128 tile GEMM, 8x8 per-thread,
// conflict-free LDS, DMA-staged B, zero spill.
// v8 post-mortem: 8x16 tile (128 acc/thread) spilled the accumulator itself
// (VGPR capped at 128; 1.75GB scratch traffic, 930us). 8x8 (v6: 68 VGPR,
// acc in AGPRs, WRITE 384KB) is the largest register-resident tile on this
// compiler -- reverted. v9 change: __launch_bounds__(256,3) so all 768
// blocks co-reside 3/CU (LDS 48KB*3=144<=160KB, regs ~132<=170) -> barrier
// stalls cross-hide between blocks (v6 occupancy was only 2 blocks/CU).
//  - lane remap: A and B reads are both 8-address b128 patterns.
//  - Gray quad-swizzle (A: ^rho per row; B: sourced via gray^-1) -> all 4
//    b128 reads/h hit 8 distinct bank-groups: zero conflicts (v6-verified).
//  - B staged by global_load_lds DMA, double-buffered; A prefetched in 4
//    NAMED float4 scalars (arrays go to scratch).
// Summation order identical to v6 -> scores bit-identical -> mask identical.
// ---------------------------------------------------------------------------
__global__ __launch_bounds__(256, 3) void score_gemm_kernel(
    const float* __restrict__ keys, const float* __restrict__ values,
    const float* __restrict__ W1a, const float* __restrict__ b1a,
    const float* __restrict__ W2a,
    const float* __restrict__ W1i, const float* __restrict__ b1i,
    const float* __restrict__ W2i,
    float* __restrict__ part)
{
    __shared__ __align__(16) float smem[KC * 128 + 2 * KC * 128];   // 48 KB
    float* A_lds = smem;                 // [KC][128] transposed, gray-swizzled
    float* Bbuf  = smem + KC * 128;      // 2 x [KC][128], linear (DMA), gray-sourced

    const int tid = threadIdx.x;
    const int lw  = tid & 63;            // lane in wave
    const int w   = tid >> 6;            // wave 0..3
    const int bid = blockIdx.x;

    const bool is_att = bid < ATT_BLOCKS;
    const int  lb     = is_att ? bid : bid - ATT_BLOCKS;
    const int  tile   = is_att ? (lb >> 2) : (lb >> 1);
    const int  pass   = is_att ? (lb & 3)  : (lb & 1);
    const int  slot   = is_att ? pass : 4 + pass;
    const int  tokb   = tile * TT;
    const int  u0     = pass * UT;
    const int  wstride = is_att ? NA : NI;

    const float* Aptr = is_att ? keys : values;
    const float* Wptr = (is_att ? W1a : W1i) + u0;
    const float* b1p  = (is_att ? b1a : b1i) + u0;
    const float* w2p  = (is_att ? W2a : W2i) + u0;

    // 8x8 octet split: this thread owns tokens 8*T8..+7, units 8*U8..+7
    const int T8 = (lw >> 3) | ((w & 1) << 3);   // 0..15
    const int U8 = (lw & 7)  | ((w >> 1) << 3);  // 0..15

    // fragment read offsets (gray of the two quads per side)
    const int qA1 = 2 * T8,      qA2 = 2 * T8 + 1;
    const int gA1 = qA1 ^ (qA1 >> 1);
    const int gA2 = qA2 ^ (qA2 >> 1);
    const int qB1 = 2 * U8,      qB2 = 2 * U8 + 1;
    const int gB1 = (qB1 ^ (qB1 >> 1)) << 2;     // float offset in row
    const int gB2 = (qB2 ^ (qB2 >> 1)) << 2;

    // A staging: thread loads tokens {at, at+32, at+64, at+96}, h-quad aq
    const int at = tid >> 3;             // 0..31
    const int aq = tid & 7;              // h-quad within chunk; rho(h)=h>>2
    const float* a_base = Aptr + (size_t)(tokb + at) * H + aq * 4;
    const int awb = (aq * 4) * 128 + (at & 3);
    const int at4 = at >> 2;
    const int q50 = at4,      q51 = at4 + 8, q52 = at4 + 16, q53 = at4 + 24;
    const int of0 = (((q50 ^ (q50 >> 1)) ^ aq) << 2);
    const int of1 = (((q51 ^ (q51 >> 1)) ^ aq) << 2);
    const int of2 = (((q52 ^ (q52 >> 1)) ^ aq) << 2);
    const int of3 = (((q53 ^ (q53 >> 1)) ^ aq) << 2);

    // B DMA: lane lw writes LDS bytes [base+16*lw) = row (lw>>5), slot (lw&31).
    // slot s must hold W quad pi(s) = gray^-1(s) (prefix-XOR).
    const int sl   = lw & 31;
    const int pisl = sl ^ (sl >> 1) ^ (sl >> 2) ^ (sl >> 3) ^ (sl >> 4);
    const float* bg = Wptr + (size_t)(lw >> 5) * wstride + pisl * 4;
    const int wrow = 8 * w;              // this wave's B row base within chunk

    float acc[8][8];
#pragma unroll
    for (int t = 0; t < 8; ++t)
#pragma unroll
        for (int u = 0; u < 8; ++u) acc[t][u] = 0.f;

    // ---- prologue: chunk 0 in flight ----
    float4 aR0 = *(const float4*)(a_base);
    float4 aR1 = *(const float4*)(a_base + (size_t)32 * H);
    float4 aR2 = *(const float4*)(a_base + (size_t)64 * H);
    float4 aR3 = *(const float4*)(a_base + (size_t)96 * H);
    dma16(bg + (size_t)(wrow + 0) * wstride, Bbuf + (wrow + 0) * 128);
    dma16(bg + (size_t)(wrow + 2) * wstride, Bbuf + (wrow + 2) * 128);
    dma16(bg + (size_t)(wrow + 4) * wstride, Bbuf + (wrow + 4) * 128);
    dma16(bg + (size_t)(wrow + 6) * wstride, Bbuf + (wrow + 6) * 128);

    for (int i = 0; i < NCH; ++i) {
        float* Bcur = Bbuf + (i & 1) * (KC * 128);
        float* Bnxt = Bbuf + ((i + 1) & 1) * (KC * 128);

        __syncthreads();     // drains loads issued a full compute-phase ago
        A_lds[awb + 0 * 128 + of0] = aR0.x;
        A_lds[awb + 1 * 128 + of0] = aR0.y;
        A_lds[awb + 2 * 128 + of0] = aR0.z;
        A_lds[awb + 3 * 128 + of0] = aR0.w;
        A_lds[awb + 0 * 128 + of1] = aR1.x;
        A_lds[awb + 1 * 128 + of1] = aR1.y;
        A_lds[awb + 2 * 128 + of1] = aR1.z;
        A_lds[awb + 3 * 128 + of1] = aR1.w;
        A_lds[awb + 0 * 128 + of2] = aR2.x;
        A_lds[awb + 1 * 128 + of2] = aR2.y;
        A_lds[awb + 2 * 128 + of2] = aR2.z;
        A_lds[awb + 3 * 128 + of2] = aR2.w;
        A_lds[awb + 0 * 128 + of3] = aR3.x;
        A_lds[awb + 1 * 128 + of3] = aR3.y;
        A_lds[awb + 2 * 128 + of3] = aR3.z;
        A_lds[awb + 3 * 128 + of3] = aR3.w;
        __syncthreads();     // nothing in vmem flight -> cheap drain

        if (i + 1 < NCH) {   // issue next chunk; lands by next top-barrier
            const int hn = (i + 1) * KC;
            aR0 = *(const float4*)(a_base + hn);
            aR1 = *(const float4*)(a_base + hn + (size_t)32 * H);
            aR2 = *(const float4*)(a_base + hn + (size_t)64 * H);
            aR3 = *(const float4*)(a_base + hn + (size_t)96 * H);
            const float* bgn = bg + (size_t)hn * wstride;
            dma16(bgn + (size_t)(wrow + 0) * wstride, Bnxt + (wrow + 0) * 128);
            dma16(bgn + (size_t)(wrow + 2) * wstride, Bnxt + (wrow + 2) * 128);
            dma16(bgn + (size_t)(wrow + 4) * wstride, Bnxt + (wrow + 4) * 128);
            dma16(bgn + (size_t)(wrow + 6) * wstride, Bnxt + (wrow + 6) * 128);
        }

#pragma unroll 8
        for (int h = 0; h < KC; ++h) {
            const int rho = h >> 2;
            float a[8], b[8];
            *(float4*)&a[0] = *(const float4*)&A_lds[h * 128 + ((gA1 ^ rho) << 2)];
            *(float4*)&a[4] = *(const float4*)&A_lds[h * 128 + ((gA2 ^ rho) << 2)];
            *(float4*)&b[0] = *(const float4*)&Bcur[h * 128 + gB1];
            *(float4*)&b[4] = *(const float4*)&Bcur[h * 128 + gB2];
#pragma unroll
            for (int t = 0; t < 8; ++t)
#pragma unroll
                for (int u = 0; u < 8; ++u)
                    acc[t][u] = fmaf(a[t], b[u], acc[t][u]);
        }
    }

    // ---- epilogue: relu + second-layer slice -> per-token partial ----
    float b1v[8], w2v[8];
    *(float4*)&b1v[0] = *(const float4*)(b1p + U8 * 8);
    *(float4*)&b1v[4] = *(const float4*)(b1p + U8 * 8 + 4);
    *(float4*)&w2v[0] = *(const float4*)(w2p + U8 * 8);
    *(float4*)&w2v[4] = *(const float4*)(w2p + U8 * 8 + 4);

    __syncthreads();                     // done with staging LDS
    float* red = smem;                   // [TT][17] padded
#pragma unroll
    for (int t = 0; t < 8; ++t) {
        float s = 0.f;
#pragma unroll
        for (int u = 0; u < 8; ++u)
            s += fmaxf(acc[t][u] + b1v[u], 0.f) * w2v[u];
        red[(T8 * 8 + t) * 17 + U8] = s;
    }
    __syncthreads();
    if (tid < TT) {
        float s = 0.f;
        for (int x = 0; x < 16; ++x) s += red[tid * 17 + x];   // fixed order
        part[(size_t)slot * NTOK + tokb + tid] = s;
    }
}

// ---------------------------------------------------------------------------
// block-wide sum (256 threads), result broadcast to all threads
// ---------------------------------------------------------------------------
__device__ __forceinline__ int block_sum(int val, int* red, int tid)
{
#pragma unroll
    for (int off = 32; off > 0; off >>= 1) val += __shfl_down(val, off);
    if ((tid & 63) == 0) red[tid >> 6] = val;
    __syncthreads();
    const int total = red[0] + red[1] + red[2] + red[3];
    __syncthreads();
    return total;
}

// ---------------------------------------------------------------------------
// Kernel 2 (v9): combine partials into scores + per-row exact top-KSEL.
// v9 select changes (both integer-exact, selection identical):
//  - 4-way wave-split histogram: scores cluster into few high-byte bins, so
//    same-address LDS atomic chains serialized across all 4 waves; per-wave
//    copies cut the hot-bin chain 4x. Summed exactly at scan init.
//  - ping-pong Hillis-Steele scans: 1 barrier/round (9 vs 17 barriers).
// ---------------------------------------------------------------------------
__global__ __launch_bounds__(256) void select_kernel(
    const float* __restrict__ part, const float* __restrict__ b2a,
    const float* __restrict__ b2i, float* __restrict__ mask)
{
    __shared__ unsigned int ks[MIDN];
    __shared__ int hist4[4 * 256];
    __shared__ int red[4];
    __shared__ int scan_a[256];
    __shared__ int scan_b[256];
    __shared__ unsigned int sh_pref;
    __shared__ int sh_r;

    const int tid = threadIdx.x;
    const int row = blockIdx.x;
    const float ba  = b2a[0];
    const float bi2 = b2i[0];

    for (int i = tid; i < MIDN; i += 256) {
        const int tok = row * SEQ + SINKN + i;
        float sa = ((part[tok] + part[NTOK + tok]) + part[2 * NTOK + tok]) + part[3 * NTOK + tok];
        float si = part[4 * NTOK + tok] + part[5 * NTOK + tok];
        const float att = 1.f / (1.f + expf(-(sa + ba)));
        const float s = 0.6f * att + 0.4f * (si + bi2);
        unsigned int u = __float_as_uint(s);
        u = (u & 0x80000000u) ? ~u : (u | 0x80000000u);   // order-preserving map
        ks[i] = u;
    }
    if (tid == 0) { sh_pref = 0u; sh_r = KSEL; }
    __syncthreads();

    // byte-radix: after 4 passes sh_pref == KSEL-th largest key value
    const int hbase = (tid >> 6) * 256;          // this wave's histogram copy
    for (int b = 3; b >= 0; --b) {
        hist4[tid] = 0; hist4[tid + 256] = 0; hist4[tid + 512] = 0; hist4[tid + 768] = 0;
        __syncthreads();
        const unsigned int hi_mask = (b == 3) ? 0u : (0xFFFFFFFFu << ((b + 1) * 8));
        const unsigned int pref = sh_pref;
        for (int i = tid; i < MIDN; i += 256) {
            const unsigned int u = ks[i];
            if ((u & hi_mask) == pref)
                atomicAdd(&hist4[hbase + ((u >> (b * 8)) & 255)], 1);
        }
        __syncthreads();

        // inclusive suffix-sum (ping-pong Hillis-Steele, 1 barrier/round)
        scan_a[tid] = hist4[tid] + hist4[tid + 256] + hist4[tid + 512] + hist4[tid + 768];
        __syncthreads();
        int* cur = scan_a;
        int* nxt = scan_b;
#pragma unroll
        for (int off = 1; off < 256; off <<= 1) {
            int v = cur[tid];
            if (tid + off < 256) v += cur[tid + off];
            nxt[tid] = v;
            __syncthreads();
            int* tmp = cur; cur = nxt; nxt = tmp;
        }
        const int r    = sh_r;
        const int sfx  = cur[tid];
        const int sfx1 = (tid < 255) ? cur[tid + 1] : 0;
        if (sfx >= r && sfx1 < r) {      // unique winner
            sh_r = r - sfx1;
            sh_pref = pref | ((unsigned int)tid << (b * 8));
        }
        __syncthreads();
    }
    const unsigned int v = sh_pref;

    const int st = tid * CHK;
    const int en = (st + CHK < MIDN) ? (st + CHK) : MIDN;

    int cgt = 0, ceq = 0;
    for (int k = st; k < en; ++k) { cgt += (ks[k] > v) ? 1 : 0; ceq += (ks[k] == v) ? 1 : 0; }
    const int total_gt = block_sum(cgt, red, tid);
    const int need = KSEL - total_gt;    // #ties to keep (>=1 by construction)

    // inclusive prefix-sum of tie counts (ping-pong), then make exclusive
    scan_a[tid] = ceq;
    __syncthreads();
    int* cur = scan_a;
    int* nxt = scan_b;
#pragma unroll
    for (int off = 1; off < 256; off <<= 1) {
        int vv = cur[tid];
        if (tid >= off) vv += cur[tid - off];
        nxt[tid] = vv;
        __syncthreads();
        int* tmp = cur; cur = nxt; nxt = tmp;
    }
    int r = cur[tid] - ceq;              // exclusive prefix

    float* mr = mask + row * SEQ;
    for (int k = st; k < en; ++k) {
        const unsigned int u = ks[k];
        bool keep = false;
        if (u > v) keep = true;
        else if (u == v) { keep = (r < need); ++r; }
        mr[SINKN + k] = keep ? 1.f : 0.f;
    }
    for (int s = tid; s < SEQ; s += 256) {
        if (s < SINKN || s >= SEQ - RECENTN) mr[s] = 1.f;
    }
}

// ---------------------------------------------------------------------------
// Kernel 3: out = concat(keys*mask, values*mask), float4 grid-stride.
// ---------------------------------------------------------------------------
__global__ __launch_bounds__(256) void apply_kernel(
    const float* __restrict__ keys, const float* __restrict__ values,
    const float* __restrict__ mask, float* __restrict__ out)
{
    const int QT = NTOK * H / 4;          // 4194304 float4 per tensor
    const int stride = gridDim.x * 256;
    for (int i4 = blockIdx.x * 256 + threadIdx.x; i4 < 2 * QT; i4 += stride) {
        const bool isv = (i4 >= QT);
        const int  j4  = isv ? (i4 - QT) : i4;
        const float m  = mask[j4 >> 8];   // 256 float4 per token row
        const float4* src = isv ? (const float4*)values : (const float4*)keys;
        const float4 x = src[j4];
        float4 y; y.x = x.x * m; y.y = x.y * m; y.z = x.z * m; y.w = x.w * m;
        ((float4*)out)[i4] = y;
    }
}

extern "C" void kernel_launch(void* const* d_in, const int* in_sizes, int n_in,
                              void* d_out, int out_size, void* d_ws, size_t ws_size,
                              hipStream_t stream)
{
    const float* keys   = (const float*)d_in[0];
    const float* values = (const float*)d_in[1];
    const float* W1a = (const float*)d_in[2];
    const float* b1a = (const float*)d_in[3];
    const float* W2a = (const float*)d_in[4];
    const float* b2a = (const float*)d_in[5];
    const float* W1i = (const float*)d_in[6];
    const float* b1i = (const float*)d_in[7];
    const float* W2i = (const float*)d_in[8];
    const float* b2i = (const float*)d_in[9];

    float* part = (float*)d_ws;            // 6*NTOK floats (att 0-3, imp 4-5)
    float* mask = part + 6 * NTOK;         // NTOK floats

    score_gemm_kernel<<<ATT_BLOCKS + IMP_BLOCKS, 256, 0, stream>>>(
        keys, values, W1a, b1a, W2a, W1i, b1i, W2i, part);
    select_kernel<<<BATCH, 256, 0, stream>>>(part, b2a, b2i, mask);
    apply_kernel<<<8192, 256, 0, stream>>>(keys, values, mask, (float*)d_out);
}